// Round 9
// baseline (21878.862 us; speedup 1.0000x reference)
//
#include <hip/hip_runtime.h>
#include <hip/hip_bf16.h>

// ---------------------------------------------------------------------------
// GRU with per-timestep BatchNorm on the input projections.
//   T=512, B=64, I=H=512.
// Round 8 -> 9: STRUCTURAL change. All cross-WG sync protocols (r2-r8)
// bottomed out at >=10us/step: agent-scope payload traffic goes to the
// HBM-class coherence point (FETCH_SIZE tracked payload word size), so every
// exchange = chain of ~900cyc hops on a downclocked chip. Since BN is hoisted
// into proj_gemm, the recurrence is embarrassingly parallel over BATCH:
// gru_scan is now BATCH-SPLIT: 4 WGs x 16 batch rows, each computes ALL 512
// columns locally. Weights (bf16, 1.5MB) stream from per-XCD L2 every step
// (L2-resident after step 1); h/rh live in LDS; 2 __syncthreads per step; NO
// inter-WG communication of any kind, no atomics, no spin loops.
// ws budget: bf16 weights 1.5MB + uz,ur (64MB) = 65.5MB < proven 96.25MB.
// uh (32MB) is packed into the SECOND HALF of out-copy2 with a per-WG
// bijective layout: WG wg's copy2 writes at step t>=256 destroy only its own
// uh entries for steps {2t-512, 2t-511} < t+1, already consumed (program
// order, same WG); different WGs' bytes are disjoint. Airtight, no sync.
// ---------------------------------------------------------------------------

using bf16x8 = __attribute__((ext_vector_type(8))) short;
using f32x4  = __attribute__((ext_vector_type(4))) float;
using fvec4  = __attribute__((ext_vector_type(4))) float;
using s16x4  = __attribute__((ext_vector_type(4))) short;

static __device__ __forceinline__ unsigned short f2bf(float f) {
  union { float ff; unsigned int i; } v; v.ff = f;
  unsigned int x = v.i;
  x += 0x7fffu + ((x >> 16) & 1u);   // RNE
  return (unsigned short)(x >> 16);
}
static __device__ __forceinline__ float h2f(unsigned short u) {
  union { unsigned short s; _Float16 h; } v; v.s = u; return (float)v.h;
}
static __device__ __forceinline__ unsigned short f2h(float f) {
  union { unsigned short s; _Float16 h; } v; v.h = (_Float16)f; return v.s;
}
static __device__ __forceinline__ float sigmoidf_(float x) {
  return 1.0f / (1.0f + __expf(-x));
}
static __device__ __forceinline__ float tanhf_(float x) {
  return 2.0f / (1.0f + __expf(-2.0f * x)) - 1.0f;
}

// uh(tp, col, b0) byte offset within d_out. Lives in copy2's second half
// (out bytes [100663296, 134217728)). Packing per (wg = b0>>4): the 32KiB
// holding uh for step-pair {2s,2s+1} occupies exactly the bytes WG wg writes
// to copy2 at step t = 256+s for its 16 rows.
static __device__ __forceinline__ size_t uh_off(int tp, int col, int b0) {
  const int wg = b0 >> 4, bu = b0 & 15;
  const int idx = ((tp & 1) << 14) + col * 32 + bu * 2;   // byte in 32KiB block
  return (size_t)100663296u + (size_t)(tp >> 1) * 131072u
       + (size_t)(wg * 16 + (idx >> 11)) * 2048u + (size_t)(idx & 2047);
}

// ---------------- phase 0: fp32 -> bf16 weight conversion ----------------
__global__ __launch_bounds__(256) void wconv(
    const float* __restrict__ a, const float* __restrict__ b,
    const float* __restrict__ c,
    unsigned short* __restrict__ oa, unsigned short* __restrict__ ob,
    unsigned short* __restrict__ oc)
{
  const int i = (blockIdx.x * 256 + threadIdx.x) * 4;   // 256 blocks -> 262144
  fvec4 va = *(const fvec4*)(a + i);
  fvec4 vb = *(const fvec4*)(b + i);
  fvec4 vc = *(const fvec4*)(c + i);
  s16x4 pa, pb, pc;
  #pragma unroll
  for (int j = 0; j < 4; ++j) {
    pa[j] = (short)f2bf(va[j]);
    pb[j] = (short)f2bf(vb[j]);
    pc[j] = (short)f2bf(vc[j]);
  }
  *(s16x4*)(oa + i) = pa;
  *(s16x4*)(ob + i) = pb;
  *(s16x4*)(oc + i) = pc;
}

// ---------------- phase 1: ub_m = BN(x @ U_m^T) + W_m_b  (fp16 out) --------
// 64x64 tile = one timestep x batch(64) x 64 cols. BN stats from fp32 accs.
// uz, ur -> linear [t][col][b] in ws; uh -> packed into out via uh_off.
__global__ __launch_bounds__(256) void proj_gemm(
    const float* __restrict__ x,
    const float* __restrict__ Uz, const float* __restrict__ Ur,
    const float* __restrict__ Uh,
    const float* __restrict__ Wzb, const float* __restrict__ Wrb,
    const float* __restrict__ Whb,
    const float* __restrict__ gamma, const float* __restrict__ beta,
    unsigned short* __restrict__ ubz, unsigned short* __restrict__ ubr,
    float* __restrict__ outb)
{
  const int mt = blockIdx.x, nt = blockIdx.y, mat = blockIdx.z;
  const float* U  = (mat == 0) ? Uz  : (mat == 1 ? Ur  : Uh);
  const float* Wb = (mat == 0) ? Wzb : (mat == 1 ? Wrb : Whb);

  __shared__ short lA[4096];   // [64][64] bf16, 128B rows, XOR-swizzled
  __shared__ short lB[4096];

  const int tid = threadIdx.x;
  const int wave = tid >> 6, lane = tid & 63;
  const int fl = lane & 15, kseg = lane >> 4;

  f32x4 acc[4];
  #pragma unroll
  for (int n = 0; n < 4; ++n) acc[n] = f32x4{0.f, 0.f, 0.f, 0.f};

  const float* xb = x + (size_t)mt * 64 * 512;
  const float* Ub = U + (size_t)nt * 64 * 512;

  for (int kt = 0; kt < 8; ++kt) {
    __syncthreads();
    #pragma unroll
    for (int c = 0; c < 2; ++c) {
      const int chunk = tid + 256 * c;       // 0..511
      const int row = chunk >> 3, kc = chunk & 7;
      const int lb = row * 128 + ((kc * 16) ^ ((row & 7) << 4));
      {
        const float* g = xb + (size_t)row * 512 + kt * 64 + kc * 8;
        fvec4 a0 = *(const fvec4*)g, a1 = *(const fvec4*)(g + 4);
        bf16x8 p;
        p[0] = (short)f2bf(a0[0]); p[1] = (short)f2bf(a0[1]);
        p[2] = (short)f2bf(a0[2]); p[3] = (short)f2bf(a0[3]);
        p[4] = (short)f2bf(a1[0]); p[5] = (short)f2bf(a1[1]);
        p[6] = (short)f2bf(a1[2]); p[7] = (short)f2bf(a1[3]);
        *(bf16x8*)((char*)lA + lb) = p;
      }
      {
        const float* g = Ub + (size_t)row * 512 + kt * 64 + kc * 8;
        fvec4 a0 = *(const fvec4*)g, a1 = *(const fvec4*)(g + 4);
        bf16x8 p;
        p[0] = (short)f2bf(a0[0]); p[1] = (short)f2bf(a0[1]);
        p[2] = (short)f2bf(a0[2]); p[3] = (short)f2bf(a0[3]);
        p[4] = (short)f2bf(a1[0]); p[5] = (short)f2bf(a1[1]);
        p[6] = (short)f2bf(a1[2]); p[7] = (short)f2bf(a1[3]);
        *(bf16x8*)((char*)lB + lb) = p;
      }
    }
    __syncthreads();
    #pragma unroll
    for (int kk = 0; kk < 2; ++kk) {
      const int ar = wave * 16 + fl;
      bf16x8 af = *(const bf16x8*)((char*)lA + ar * 128 +
                    ((kk * 64 + kseg * 16) ^ ((ar & 7) << 4)));
      #pragma unroll
      for (int n = 0; n < 4; ++n) {
        const int br = n * 16 + fl;
        bf16x8 bfr = *(const bf16x8*)((char*)lB + br * 128 +
                      ((kk * 64 + kseg * 16) ^ ((br & 7) << 4)));
        acc[n] = __builtin_amdgcn_mfma_f32_16x16x32_bf16(af, bfr, acc[n], 0, 0, 0);
      }
    }
  }

  // ---- BN epilogue: exact batch stats (all 64 rows), from fp32 accs ----
  float sn[4], qn[4];
  #pragma unroll
  for (int n = 0; n < 4; ++n) {
    sn[n] = acc[n][0] + acc[n][1] + acc[n][2] + acc[n][3];
    qn[n] = acc[n][0]*acc[n][0] + acc[n][1]*acc[n][1]
          + acc[n][2]*acc[n][2] + acc[n][3]*acc[n][3];
    sn[n] += __shfl_xor(sn[n], 16); qn[n] += __shfl_xor(qn[n], 16);
    sn[n] += __shfl_xor(sn[n], 32); qn[n] += __shfl_xor(qn[n], 32);
  }
  __syncthreads();
  float* sArr = (float*)lA;
  float* qArr = (float*)lB;
  if (kseg == 0) {
    #pragma unroll
    for (int n = 0; n < 4; ++n) {
      sArr[wave * 64 + n * 16 + fl] = sn[n];
      qArr[wave * 64 + n * 16 + fl] = qn[n];
    }
  }
  __syncthreads();

  const int c0 = nt * 64;
  const int b0 = wave * 16 + kseg * 4;     // batch base for this thread
  #pragma unroll
  for (int n = 0; n < 4; ++n) {
    const int idx = n * 16 + fl;
    const float s = sArr[idx] + sArr[64+idx] + sArr[128+idx] + sArr[192+idx];
    const float q = qArr[idx] + qArr[64+idx] + qArr[128+idx] + qArr[192+idx];
    const float mu = s * 0.015625f;
    const float rs = rsqrtf(q * 0.015625f - mu * mu + 1e-5f);
    const int col = c0 + idx;
    const float gb  = gamma[col] * rs;
    const float ofs = beta[col] + Wb[col] - gb * mu;   // fold W bias here
    s16x4 pk;
    #pragma unroll
    for (int i = 0; i < 4; ++i)
      pk[i] = (short)f2h(gb * acc[n][i] + ofs);
    if (mat == 2) {
      *(s16x4*)((char*)outb + uh_off(mt, col, b0)) = pk;
    } else {
      unsigned short* uo = (mat == 0) ? ubz : ubr;
      *(s16x4*)(uo + ((size_t)mt * 512 + col) * 64 + b0) = pk;
    }
  }
}

// ---------------- phase 2: batch-split GRU scan (no inter-WG comm) ---------
// 4 WGs x 512 threads (8 waves). WG wg owns batch rows [wg*16, wg*16+16).
// Wave w owns cols [w*64, w*64+64) = 4 N-tiles. Weights streamed global->
// VGPR (L2-hit after step 1), h/rh in LDS (XOR-swizzled bf16 [16][512]).
__global__ __launch_bounds__(512) void gru_scan(
    const float* __restrict__ h0,
    const unsigned short* __restrict__ wz, const unsigned short* __restrict__ wr,
    const unsigned short* __restrict__ wh,
    const unsigned short* __restrict__ ubz, const unsigned short* __restrict__ ubr,
    float* __restrict__ out)
{
  const int wg = blockIdx.x;
  const int tid = threadIdx.x;
  const int wave = tid >> 6, lane = tid & 63;
  const int fl = lane & 15, ks = lane >> 4;
  const int n0 = wave * 64;                 // this wave's column base

  __shared__ short lh[8192];    // [16 rows][512 k] bf16, XOR-swizzled rows
  __shared__ short lrh[8192];

  // init: hown fp32 (C-layout) + lh
  float hown[4][4];
  #pragma unroll
  for (int nt = 0; nt < 4; ++nt) {
    const int col = n0 + nt * 16 + fl;
    #pragma unroll
    for (int i = 0; i < 4; ++i) {
      const int b = ks * 4 + i;
      const float v = h0[(size_t)(wg * 16 + b) * 512 + col];
      hown[nt][i] = v;
      *(short*)((char*)lh + b * 1024 + ((col * 2) ^ ((b & 7) << 4))) =
          (short)f2bf(v);
    }
  }
  __syncthreads();

  // u for t=0
  s16x4 ucz[4], ucr[4], uch[4];
  #pragma unroll
  for (int nt = 0; nt < 4; ++nt) {
    const int col = n0 + nt * 16 + fl;
    const size_t o = ((size_t)col) * 64 + wg * 16 + ks * 4;
    ucz[nt] = *(const s16x4*)(ubz + o);
    ucr[nt] = *(const s16x4*)(ubr + o);
    uch[nt] = *(const s16x4*)((const char*)out + uh_off(0, col, wg * 16 + ks * 4));
  }

  const unsigned short* Wab[2] = {wz, wr};

  for (int t = 0; t < 512; ++t) {
    // ---- phase A: h A-frags, z+r GEMMs (streamed B, 1-ahead pipelined) ----
    bf16x8 A[16];
    #pragma unroll
    for (int kk = 0; kk < 16; ++kk)
      A[kk] = *(const bf16x8*)((const char*)lh + fl * 1024 +
                ((kk * 64 + ks * 16) ^ ((fl & 7) << 4)));

    f32x4 ga[2][4];
    #pragma unroll
    for (int m = 0; m < 2; ++m)
      #pragma unroll
      for (int n = 0; n < 4; ++n) ga[m][n] = f32x4{0.f, 0.f, 0.f, 0.f};

    bf16x8 Pa[8], Pb[8];
    // halfblock hb: mat=hb>>3, nt=(hb>>1)&3, half=hb&1 ; 8 frags each
    {
      const unsigned short* bp = Wab[0] + ((n0 + fl) * 512 + ks * 8);
      #pragma unroll
      for (int j = 0; j < 8; ++j) Pa[j] = *(const bf16x8*)(bp + j * 32);
    }
    #pragma unroll
    for (int hb = 0; hb < 16; ++hb) {
      if (hb + 1 < 16) {
        const int h2 = hb + 1;
        const int m2 = h2 >> 3, nt2 = (h2 >> 1) & 3, hf2 = h2 & 1;
        const unsigned short* bp =
            Wab[m2] + ((n0 + nt2 * 16 + fl) * 512 + hf2 * 256 + ks * 8);
        bf16x8* nxt = (hb & 1) ? Pa : Pb;
        #pragma unroll
        for (int j = 0; j < 8; ++j) nxt[j] = *(const bf16x8*)(bp + j * 32);
      }
      bf16x8* cur = (hb & 1) ? Pb : Pa;
      const int mat = hb >> 3, nt = (hb >> 1) & 3, half = hb & 1;
      #pragma unroll
      for (int j = 0; j < 8; ++j)
        ga[mat][nt] = __builtin_amdgcn_mfma_f32_16x16x32_bf16(
            A[half * 8 + j], cur[j], ga[mat][nt], 0, 0, 0);
    }

    // gates z, r; write rh to LDS
    float z4[4][4];
    #pragma unroll
    for (int nt = 0; nt < 4; ++nt) {
      const int col = n0 + nt * 16 + fl;
      #pragma unroll
      for (int i = 0; i < 4; ++i) {
        const float z = sigmoidf_(ga[0][nt][i] + h2f((unsigned short)ucz[nt][i]));
        const float r = sigmoidf_(ga[1][nt][i] + h2f((unsigned short)ucr[nt][i]));
        z4[nt][i] = z;
        const int b = ks * 4 + i;
        *(short*)((char*)lrh + b * 1024 + ((col * 2) ^ ((b & 7) << 4))) =
            (short)f2bf(r * hown[nt][i]);
      }
    }
    __syncthreads();

    // ---- phase B: rh A-frags, n GEMM, h update, outputs ----
    bf16x8 A2[16];
    #pragma unroll
    for (int kk = 0; kk < 16; ++kk)
      A2[kk] = *(const bf16x8*)((const char*)lrh + fl * 1024 +
                 ((kk * 64 + ks * 16) ^ ((fl & 7) << 4)));

    f32x4 hc[4];
    #pragma unroll
    for (int n = 0; n < 4; ++n) hc[n] = f32x4{0.f, 0.f, 0.f, 0.f};

    {
      const unsigned short* bp = wh + ((n0 + fl) * 512 + ks * 8);
      #pragma unroll
      for (int j = 0; j < 8; ++j) Pa[j] = *(const bf16x8*)(bp + j * 32);
    }
    #pragma unroll
    for (int hb = 0; hb < 8; ++hb) {
      if (hb + 1 < 8) {
        const int h2 = hb + 1;
        const int nt2 = h2 >> 1, hf2 = h2 & 1;
        const unsigned short* bp =
            wh + ((n0 + nt2 * 16 + fl) * 512 + hf2 * 256 + ks * 8);
        bf16x8* nxt = (hb & 1) ? Pa : Pb;
        #pragma unroll
        for (int j = 0; j < 8; ++j) nxt[j] = *(const bf16x8*)(bp + j * 32);
      }
      bf16x8* cur = (hb & 1) ? Pb : Pa;
      const int nt = hb >> 1, half = hb & 1;
      #pragma unroll
      for (int j = 0; j < 8; ++j)
        hc[nt] = __builtin_amdgcn_mfma_f32_16x16x32_bf16(
            A2[half * 8 + j], cur[j], hc[nt], 0, 0, 0);
    }

    // u prefetch for t+1 BEFORE the out writes (uh lives inside out copy2;
    // writes at step t destroy only uh steps {2t-512, 2t-511} < t+1).
    if (t + 1 < 512) {
      #pragma unroll
      for (int nt = 0; nt < 4; ++nt) {
        const int col = n0 + nt * 16 + fl;
        const size_t o = ((size_t)(t + 1) * 512 + col) * 64 + wg * 16 + ks * 4;
        ucz[nt] = *(const s16x4*)(ubz + o);
        ucr[nt] = *(const s16x4*)(ubr + o);
        uch_nxt_guard:;
      }
    }
    s16x4 uhn[4];
    if (t + 1 < 512) {
      #pragma unroll
      for (int nt = 0; nt < 4; ++nt) {
        const int col = n0 + nt * 16 + fl;
        uhn[nt] = *(const s16x4*)((const char*)out +
                    uh_off(t + 1, col, wg * 16 + ks * 4));
      }
    }

    // h update + out writes
    #pragma unroll
    for (int nt = 0; nt < 4; ++nt) {
      const int col = n0 + nt * 16 + fl;
      #pragma unroll
      for (int i = 0; i < 4; ++i) {
        const float nb = tanhf_(hc[nt][i] + h2f((unsigned short)uch[nt][i]));
        const float hn = (1.f - z4[nt][i]) * hown[nt][i] + z4[nt][i] * nb;
        hown[nt][i] = hn;
        const int b = ks * 4 + i;
        *(short*)((char*)lh + b * 1024 + ((col * 2) ^ ((b & 7) << 4))) =
            (short)f2bf(hn);
        const size_t o = ((size_t)t * 64 + wg * 16 + b) * 512 + col;
        out[o] = hn;
        out[16777216 + o] = hn;
      }
    }
    if (t + 1 < 512) {
      #pragma unroll
      for (int nt = 0; nt < 4; ++nt) uch[nt] = uhn[nt];
    }
    __syncthreads();
  }
}

extern "C" void kernel_launch(void* const* d_in, const int* in_sizes, int n_in,
                              void* d_out, int out_size, void* d_ws, size_t ws_size,
                              hipStream_t stream) {
  (void)in_sizes; (void)n_in; (void)out_size; (void)ws_size;
  const float* x   = (const float*)d_in[0];
  const float* h0  = (const float*)d_in[1];
  const float* Wz  = (const float*)d_in[2];
  const float* Wzb = (const float*)d_in[3];
  const float* Uz  = (const float*)d_in[4];
  const float* Wr  = (const float*)d_in[6];
  const float* Wrb = (const float*)d_in[7];
  const float* Ur  = (const float*)d_in[8];
  const float* Wh  = (const float*)d_in[10];
  const float* Whb = (const float*)d_in[11];
  const float* Uh  = (const float*)d_in[12];
  const float* gam = (const float*)d_in[14];
  const float* bet = (const float*)d_in[15];
  float* out = (float*)d_out;

  char* ws = (char*)d_ws;
  // ws layout (max 65.5MB, well under proven 96.25MB ceiling):
  //   [0, 512K)        Wz bf16 [col][k]
  //   [512K, 1M)       Wr bf16
  //   [1M, 1.5M)       Wh bf16
  //   [1.5M, 33.5M)    ub_z fp16 [t][col][b]
  //   [33.5M, 65.5M)   ub_r fp16
  // ub_h lives inside d_out copy2 second half (see uh_off).
  unsigned short* wz16 = (unsigned short*)(ws);
  unsigned short* wr16 = (unsigned short*)(ws + 524288);
  unsigned short* wh16 = (unsigned short*)(ws + 1048576);
  unsigned short* uzb  = (unsigned short*)(ws + 1572864);
  unsigned short* urb  = (unsigned short*)(ws + 1572864 + 33554432);

  wconv<<<dim3(256), 256, 0, stream>>>(Wz, Wr, Wh, wz16, wr16, wh16);
  dim3 gp(512, 8, 3);
  proj_gemm<<<gp, 256, 0, stream>>>(x, Uz, Ur, Uh, Wzb, Wrb, Whb,
                                    gam, bet, uzb, urb, out);
  gru_scan<<<dim3(4), 512, 0, stream>>>(h0, wz16, wr16, wh16, uzb, urb, out);
}